// Round 5
// baseline (445.614 us; speedup 1.0000x reference)
//
#include <hip/hip_runtime.h>

// CfCHead: B=64, S=2048, H=1024 sequential nonlinear scan.
// Round-8 (= r7 + compile fix: float4 arrays instead of token-pasted
// register names; no ## against member access).
// Theory (from r3-r6 evidence): trans issue ~3-4cy, so issue/step is only
// ~80cy of the measured 255cy -> ~70% is in-order dependency stall on
// exp2/rcp latencies. Fix: place independent work BETWEEN producers and
// consumers of long-latency ops:
//  - per step u: issue exp2(m) FIRST; fill its shadow with the NEXT
//    chunk's gate work (3-stage pipeline: exp2-issue at u, rcps at u+1,
//    finish at u+2 -> no op waits on a fresh trans) plus exp2(Carr[u-1]);
//    consume En at the BOTTOM of the step.
//  - sigmoid(c)/h drained in a pipelined batch (paired rcps, r4 form).
//  - x register-prefetched TWO chunks ahead (wave-uniform float4s).
// Same proven shell: 256 blocks x 512 thr, waves 0-3 chains, 4-7
// projection, CH=16, one barrier/chunk, conflict-free LDS (HSTR=17).

#define Bv   64
#define Sv   2048
#define Hv   1024
#define TPB  256      // producer (chain) threads per block
#define NT   512      // total threads per block
#define CH   16       // chunk (time steps per barrier)
#define HSTR 17       // LDS row stride (floats), odd -> conflict-free
#define HBUF (TPB * HSTR)

#define L2E   1.44269504088896340736f
#define NL2E (-1.44269504088896340736f)
#define LN2   0.69314718055994530942f
#define KNU   0.014426950408889634f     /* 0.01*L2E          */
#define CREB  0.692493619626702435f     /* 16*0.03*L2E       */
#define LOG2_001 (-6.6438561897747247f) /* log2(0.01)        */
#define LOG2_L2E 0.52876637294489777f   /* log2(L2E)         */

__device__ __forceinline__ float fexp2(float x) { return __builtin_amdgcn_exp2f(x); }
__device__ __forceinline__ float frcp(float x)  { return __builtin_amdgcn_rcpf(x); }

// out[b*S*2 + t*2 + k] = proj_b[k]  (clears 0xAA poison; scan atomically adds)
__global__ __launch_bounds__(256) void init_out(const float* __restrict__ proj_b,
                                                float* __restrict__ out) {
    int i = blockIdx.x * 256 + threadIdx.x;
    out[i] = proj_b[i & 1];
}

// compile-time component select (u constant after unroll -> stays in regs)
#define XCOMP(qv, v) ((v)==0?(qv).x:(v)==1?(qv).y:(v)==2?(qv).z:(qv).w)
#define XGET(X, u)   XCOMP(X[(u) >> 2], (u) & 3)

// finish gate step w from the 3-stage pipeline (stages in sg*/sr* arrays)
#define NG_FIN(w, NGF, NGIG, NGOA, NGS, NGIL)                                   \
    NGF[w]  = sgf[w];                                                           \
    NGOA[w] = sgo[w];                                                           \
    NGIG[w] = sgi[w] * srg[w];                 /* L2E*e^pi*sig_g */             \
    NGIL[w] = fmaf(srl[w], -0.01f, 1.0f);      /* 1/(1+.01*sig_l) */            \
    NGS[w]  = fmaf(sgo[w], 100.0f, fmaf(sgi[w], LN2, sgf[w])); /* e^i+e^f+e^o */

#define CONSUME_PROJ(T0, PAR)                                                   \
    if (tid >= TPB) {                                                           \
        const float* __restrict__ hb  = &hlds[(PAR) * HBUF];                    \
        const float* __restrict__ pwk = &pwlds[rk * TPB];                       \
        float sum = 0.0f;                                                       \
        _Pragma("unroll")                                                       \
        for (int i2 = 0; i2 < 32; ++i2) {                                       \
            const int v  = (i2 + 4 * rseg) & 31;                                \
            const int jj = rseg * 32 + v;                                       \
            sum = fmaf(hb[jj * HSTR + rt], pwk[jj], sum);                       \
        }                                                                       \
        sum += __shfl_xor(sum, 1, 64);                                          \
        sum += __shfl_xor(sum, 2, 64);                                          \
        sum += __shfl_xor(sum, 4, 64);                                          \
        if (rseg == 0) atomicAdd(&orow[((T0) + rt) * 2 + rk], sum);             \
    }

// One chunk: consume gates C*, produce gates N* (for chunk T0/CH+1 using XU),
// prefetch x for chunk T0/CH+2 into XL, publish h, then projection.
#define CHUNK_BODY(T0, PAR, CGF, CGIG, CGOA, CGS, CGIL,                         \
                   NGF, NGIG, NGOA, NGS, NGIL, XU, XL)                          \
    if (tid < TPB) {                                                            \
        { const int tx = ((T0) + 2 * CH) & (Sv - 1);                            \
          XL[0] = *reinterpret_cast<const float4*>(xrow + tx);                  \
          XL[1] = *reinterpret_cast<const float4*>(xrow + tx + 4);              \
          XL[2] = *reinterpret_cast<const float4*>(xrow + tx + 8);              \
          XL[3] = *reinterpret_cast<const float4*>(xrow + tx + 12); }           \
        float Carr[CH], Pa[CH], eA[CH];                                         \
        float sgi[CH], sgf[CH], sgo[CH], seg[CH], sel[CH], srg[CH], srl[CH];    \
        _Pragma("unroll")                                                       \
        for (int u = 0; u < CH; ++u) {                                          \
            const float EnN = fexp2(m);          /* issue early */              \
            { const float xc = XGET(XU, u);      /* shadow: next-gate stage1 */ \
              sgi[u] = fexp2(fmaf(xc, wi2, bi2));                               \
              sgf[u] = fexp2(fmaf(xc, wf2, bf2));                               \
              sgo[u] = fexp2(fmaf(xc, wo2, bo2));                               \
              seg[u] = fexp2(fmaf(xc, wg2, bg2));                               \
              sel[u] = fexp2(fmaf(xc, wl2, bl2)); }                             \
            if (u >= 1) {                        /* stage2: rcps (+1 old) */    \
                srg[u-1] = frcp(1.0f  + seg[u-1]);                              \
                srl[u-1] = frcp(1.01f + sel[u-1]);                              \
                eA[u-1]  = fexp2(Carr[u-1]);                                    \
            }                                                                   \
            if (u >= 2) { NG_FIN(u-2, NGF, NGIG, NGOA, NGS, NGIL) }             \
            { const float Enu = EnN * CUP[u];    /* consume at bottom */        \
              const float ef  = CGF[u] * Enu;                                   \
              C = fmaf(ef, C, -(CGIG[u] * Enu));                                \
              Carr[u] = C;                                                      \
              Pa[u]   = CGOA[u] * Enu;                                          \
              m = fmaf(CGS[u] * Enu, -KNU, m); }                                \
        }                                                                       \
        m += CREB;                               /* drift rebase */             \
        srg[CH-1] = frcp(1.0f  + seg[CH-1]);     /* drain stages */             \
        srl[CH-1] = frcp(1.01f + sel[CH-1]);                                    \
        eA[CH-1]  = fexp2(Carr[CH-1]);                                          \
        NG_FIN(CH-2, NGF, NGIG, NGOA, NGS, NGIL)                                \
        float* __restrict__ hrow = &hlds[(PAR) * HBUF + tid * HSTR];            \
        _Pragma("unroll")                                                       \
        for (int p = 0; p < CH / 2; ++p) {                                      \
            const float A0 = 1.0f + eA[2*p];     /* 1+e^{-c}, in (1,2] */       \
            const float A1 = 1.0f + eA[2*p+1];                                  \
            const float rr = frcp(A0 * A1);      /* one rcp, two steps */       \
            h = fmaf(Pa[2*p],   rr * A1, h) * CGIL[2*p];   hrow[2*p]   = h;     \
            h = fmaf(Pa[2*p+1], rr * A0, h) * CGIL[2*p+1]; hrow[2*p+1] = h;     \
            if (p == 5) { NG_FIN(CH-1, NGF, NGIG, NGOA, NGS, NGIL) }            \
        }                                                                       \
    }                                                                           \
    __syncthreads();                                                            \
    CONSUME_PROJ(T0, PAR)

__global__ __launch_bounds__(NT, 2) void cfc_scan(
    const float* __restrict__ x_codes,
    const float* __restrict__ Wi_w, const float* __restrict__ Wi_b,
    const float* __restrict__ Wf_w, const float* __restrict__ Wf_b,
    const float* __restrict__ Wo_w, const float* __restrict__ Wo_b,
    const float* __restrict__ Wg_w, const float* __restrict__ Wg_b,
    const float* __restrict__ Wl_w, const float* __restrict__ Wl_b,
    const float* __restrict__ proj_w,
    const float* __restrict__ n_init,
    float* __restrict__ out)
{
    __shared__ float hlds[2 * HBUF];    // double-buffered raw h, [par][j][u]
    __shared__ float pwlds[2 * TPB];    // proj_w staged, [k][j_local]

    const int b   = blockIdx.x >> 2;
    const int q   = blockIdx.x & 3;
    const int tid = threadIdx.x;

    const float* __restrict__ xrow = x_codes + b * Sv;
    float* __restrict__ orow = out + b * (Sv * 2);

    // ---- consumer setup (waves 4-7) ----
    const int ct   = tid - TPB;
    const int rk   = (ct >> 7) & 1;
    const int rt   = (ct >> 3) & 15;
    const int rseg = ct & 7;
    if (tid >= TPB) {
        pwlds[ct]       = proj_w[q * TPB + ct];
        pwlds[TPB + ct] = proj_w[Hv + q * TPB + ct];
    }

    // ---- producer setup (waves 0-3): fold all affine maps into weights ----
    float wi2 = 0, bi2 = 0, wf2 = 0, bf2 = 0, wo2 = 0, bo2 = 0;
    float wg2 = 0, bg2 = 0, wl2 = 0, bl2 = 0;
    float m = 0, C = 0, h = 0;
    if (tid < TPB) {
        const int j = q * TPB + tid;
        const float wi = Wi_w[j], bi = Wi_b[j];
        const float wf = Wf_w[j], bf = Wf_b[j];
        const float wo = Wo_w[j], bo = Wo_b[j];
        const float wg = Wg_w[j], bg = Wg_b[j];
        const float wl = Wl_w[j], bl = Wl_b[j];
        // pre = ((code-65)/100)*w + b ; exponent_arg = pre*L2E = code*w' + b'
        // gi carries an extra L2E (bias += log2(L2E)): gS uses gi*LN2.
        wi2 = wi * KNU;  bi2 = fmaf(-0.65f, wi, bi) * L2E + LOG2_L2E;
        wf2 = wf * KNU;  bf2 = fmaf(-0.65f, wf, bf) * L2E;
        wo2 = wo * KNU;  bo2 = fmaf(-0.65f, wo, bo) * L2E + LOG2_001; // 0.01*e^pre_o
        wg2 = -wg * KNU; bg2 = fmaf(-0.65f, wg, bg) * NL2E;           // e^{-pre_g}
        wl2 = -wl * KNU; bl2 = fmaf(-0.65f, wl, bl) * NL2E;           // e^{-pre_l}
        m  = n_init[j] * NL2E;   // m = -n*L2E (drift-free form)
    }

    // 2^{0.03*L2E*u} = e^{0.03u}: per-step drift of e^{-n}, compile-time
    static const float CUP[CH] = {
        1.0f,        1.03045453f, 1.06183655f, 1.09417428f,
        1.12749685f, 1.16183424f, 1.19721736f, 1.23367806f,
        1.27124915f, 1.30996445f, 1.34985881f, 1.39096813f,
        1.43332941f, 1.47698079f, 1.52196156f, 1.56831219f };

    // gate arrays (A = even chunks' consume-set first) + x prefetch regs
    float GAf[CH], GAig[CH], GAoa[CH], GAs[CH], GAil[CH];
    float GBf[CH], GBig[CH], GBoa[CH], GBs[CH], GBil[CH];
    float4 xA[4], xB[4];

    if (tid < TPB) {
        // prime gates for chunk 0 into GA (one-time, no pipelining needed)
        #pragma unroll
        for (int u4 = 0; u4 < 4; ++u4) {
            const float4 xq = *reinterpret_cast<const float4*>(xrow + 4 * u4);
            #pragma unroll
            for (int v = 0; v < 4; ++v) {
                const int u = 4 * u4 + v;
                const float xc = XCOMP(xq, v);
                const float gi = fexp2(fmaf(xc, wi2, bi2));
                const float gf = fexp2(fmaf(xc, wf2, bf2));
                const float go = fexp2(fmaf(xc, wo2, bo2));
                const float eg = fexp2(fmaf(xc, wg2, bg2));
                const float el = fexp2(fmaf(xc, wl2, bl2));
                GAf[u]  = gf;
                GAoa[u] = go;
                GAig[u] = gi * frcp(1.0f + eg);
                GAil[u] = fmaf(frcp(1.01f + el), -0.01f, 1.0f);
                GAs[u]  = fmaf(go, 100.0f, fmaf(gi, LN2, gf));
            }
        }
        // preload xA = x of chunk 1 (consumed by chunk-0 body's gate work)
        xA[0] = *reinterpret_cast<const float4*>(xrow + CH);
        xA[1] = *reinterpret_cast<const float4*>(xrow + CH + 4);
        xA[2] = *reinterpret_cast<const float4*>(xrow + CH + 8);
        xA[3] = *reinterpret_cast<const float4*>(xrow + CH + 12);
    }

    for (int t0 = 0; t0 < Sv; t0 += 2 * CH) {
        CHUNK_BODY(t0,      0, GAf, GAig, GAoa, GAs, GAil,
                               GBf, GBig, GBoa, GBs, GBil, xA, xB)
        CHUNK_BODY(t0 + CH, 1, GBf, GBig, GBoa, GBs, GBil,
                               GAf, GAig, GAoa, GAs, GAil, xB, xA)
    }
}

extern "C" void kernel_launch(void* const* d_in, const int* in_sizes, int n_in,
                              void* d_out, int out_size, void* d_ws, size_t ws_size,
                              hipStream_t stream) {
    const float* x_codes = (const float*)d_in[0];
    const float* Wi_w = (const float*)d_in[1];
    const float* Wi_b = (const float*)d_in[2];
    const float* Wf_w = (const float*)d_in[3];
    const float* Wf_b = (const float*)d_in[4];
    const float* Wo_w = (const float*)d_in[5];
    const float* Wo_b = (const float*)d_in[6];
    const float* Wg_w = (const float*)d_in[7];
    const float* Wg_b = (const float*)d_in[8];
    const float* Wl_w = (const float*)d_in[9];
    const float* Wl_b = (const float*)d_in[10];
    const float* proj_w = (const float*)d_in[11];
    const float* proj_b = (const float*)d_in[12];
    const float* n_init = (const float*)d_in[13];
    float* out = (float*)d_out;

    init_out<<<out_size / 256, 256, 0, stream>>>(proj_b, out);
    cfc_scan<<<Bv * (Hv / TPB), NT, 0, stream>>>(
        x_codes, Wi_w, Wi_b, Wf_w, Wf_b, Wo_w, Wo_b, Wg_w, Wg_b, Wl_w, Wl_b,
        proj_w, n_init, out);
}

// Round 6
// 386.589 us; speedup vs baseline: 1.1527x; 1.1527x over previous
//
#include <hip/hip_runtime.h>

// CfCHead: B=64, S=2048, H=1024 sequential nonlinear scan.
// Round-9: 3-group wave pipeline (r5 done right, informed by r8's spill).
//  Model (r3-r8): single-wave issue ~95cy/step vs 255cy measured -> ~60%
//  in-order dep stall; chain waves are pinned at 1 per SIMD, so the fix is
//  moving all non-recurrent work to OTHER waves on the same SIMD:
//   G0 (waves 0-3, 1/SIMD): pure recurrence. Per step: read gate float4
//       (contiguous 16B/lane, conflict-free), 5 VALU + 1 exp2
//       (m = fmaf(gSK, En, m); En = exp2(m) -- CUP drift folded into the
//       gate-side exp2 biases so NO muls sit on the m-chain), write {C,Pa}.
//   G1 (waves 4-7): 4 exp2 + 1 rcp per step, pack {gFK,gIGK,PaK,gSK} ->
//       gate tile for chunk p+1.
//   G2 (waves 8-11): lambda gate + sigmoid(c) (paired rcps) + serial
//       h-chain for chunk p-1 (reads {C,Pa} published at the barrier),
//       h -> LDS, projection of chunk p-2 (r3's conflict-free pattern).
//  One barrier per phase (258 total). Every LDS handoff crosses exactly
//  one barrier -> no LDS latency on any serial path. Per-group registers
//  <= ~40 -> no spill (r8's failure). 12 waves/CU, one of each group per
//  SIMD: stalls of one group filled by the other two.

#define Bv   64
#define Sv   2048
#define Hv   1024
#define TPG  256     // threads per group (= chains per block)
#define NT   768
#define CH   8       // chunk (time steps per phase)
#define NCH  (Sv / CH)   // 256

#define L2E   1.44269504088896340736f
#define NL2E (-1.44269504088896340736f)
#define LN2   0.69314718055994530942f
#define KNU   0.014426950408889634f      /* 0.01*L2E        */
#define N100KNU (-1.4426950408889634f)   /* -100*KNU        */
#define CREB8 0.34624680981335122f       /* 8*0.03*L2E      */
#define DRFT  0.043280851226668903f      /* 0.03*L2E        */
#define LOG2_001 (-6.6438561897747247f)  /* log2(0.01)      */
#define LOG2_L2E 0.52876637294489777f    /* log2(L2E)       */

__device__ __forceinline__ float fexp2(float x) { return __builtin_amdgcn_exp2f(x); }
__device__ __forceinline__ float frcp(float x)  { return __builtin_amdgcn_rcpf(x); }

// out[b*S*2 + t*2 + k] = proj_b[k]  (clears 0xAA poison; scan atomically adds)
__global__ __launch_bounds__(256) void init_out(const float* __restrict__ proj_b,
                                                float* __restrict__ out) {
    int i = blockIdx.x * 256 + threadIdx.x;
    out[i] = proj_b[i & 1];
}

// G1: produce gate tile for chunk P into buf P&1.
//  gFK = e^{pre_f}*CUPu ; gIGK = L2E*e^{pre_i}*sig_g*CUPu ;
//  PaK = 0.01*e^{pre_o}*CUPu ; gSK = -KNU*(e^pi+e^pf+e^po)*CUPu
//  (CUPu = e^{0.03u} folded into the per-u exp2 biases, zero extra muls)
#define GATEBODY(P)                                                             \
    {                                                                           \
        const int t1 = (P) * CH;                                                \
        const float4 xq0 = *reinterpret_cast<const float4*>(xrow + t1);         \
        const float4 xq1 = *reinterpret_cast<const float4*>(xrow + t1 + 4);     \
        float* gw = &glds[(((P) & 1) * CH) * 1024 + lt * 4];                    \
        _Pragma("unroll")                                                       \
        for (int u = 0; u < CH; ++u) {                                          \
            const float xc = (u < 4)                                            \
                ? ((u==0)?xq0.x:(u==1)?xq0.y:(u==2)?xq0.z:xq0.w)                \
                : ((u==4)?xq1.x:(u==5)?xq1.y:(u==6)?xq1.z:xq1.w);               \
            const float gi = fexp2(fmaf(xc, wi2, bi2u[u]));                     \
            const float gf = fexp2(fmaf(xc, wf2, bf2u[u]));                     \
            const float go = fexp2(fmaf(xc, wo2, bo2u[u]));                     \
            const float eg = fexp2(fmaf(xc, wg2, bg2));                         \
            const float rg = frcp(1.0f + eg);                                   \
            float4 v;                                                           \
            v.x = gf;                                                           \
            v.y = gi * rg;                                                      \
            v.z = go;                                                           \
            v.w = fmaf(go, N100KNU, fmaf(gi, -0.01f, gf * (-KNU)));             \
            *reinterpret_cast<float4*>(gw + u * 1024) = v;                      \
        }                                                                       \
    }

__global__ __launch_bounds__(NT, 1) void cfc_scan(
    const float* __restrict__ x_codes,
    const float* __restrict__ Wi_w, const float* __restrict__ Wi_b,
    const float* __restrict__ Wf_w, const float* __restrict__ Wf_b,
    const float* __restrict__ Wo_w, const float* __restrict__ Wo_b,
    const float* __restrict__ Wg_w, const float* __restrict__ Wg_b,
    const float* __restrict__ Wl_w, const float* __restrict__ Wl_b,
    const float* __restrict__ proj_w,
    const float* __restrict__ n_init,
    float* __restrict__ out)
{
    // glds[buf][u][j][4]  gate tiles          (65536 B)
    // cpa [buf][pp][j][4] {C,Pa} pair tiles   (32768 B)
    // hlds[buf][j*9+u]    h, conflict-free    (18432 B)
    // pwlds[k][j]         proj_w staged       ( 2048 B)
    __shared__ __align__(16) float glds[2 * CH * 1024];
    __shared__ __align__(16) float cpa[2 * 4 * 1024];
    __shared__ float hlds[2 * 2304];
    __shared__ float pwlds[2 * TPG];

    const int b   = blockIdx.x >> 2;
    const int q   = blockIdx.x & 3;
    const int tid = threadIdx.x;
    const int grp = tid >> 8;        // 0=chain, 1=gates, 2=h+proj
    const int lt  = tid & 255;

    const float* __restrict__ xrow = x_codes + b * Sv;
    float* __restrict__ orow = out + b * (Sv * 2);

    // G0 state
    float m = 0, En = 0, C = 0;
    // G1 constants (biased per-u: CUP drift folded into exp2 args)
    float wi2 = 0, wf2 = 0, wo2 = 0, wg2 = 0, bg2 = 0;
    float bi2u[CH], bf2u[CH], bo2u[CH];
    // G2 constants/state
    float wl2 = 0, bl2 = 0, h = 0;
    const int rk = lt >> 7, rt = (lt >> 4) & 7, rseg = lt & 15;

    if (grp == 0) {
        m  = n_init[q * TPG + lt] * NL2E;   // m = -n*L2E (drift-free)
        En = fexp2(m);
        #pragma unroll
        for (int u = 0; u < CH; ++u) { bi2u[u]=0; bf2u[u]=0; bo2u[u]=0; }
    } else if (grp == 1) {
        const int j = q * TPG + lt;
        const float wi = Wi_w[j], bi = Wi_b[j];
        const float wf = Wf_w[j], bf = Wf_b[j];
        const float wo = Wo_w[j], bo = Wo_b[j];
        const float wg = Wg_w[j], bg = Wg_b[j];
        // pre = ((code-65)/100)*w + b ; exp2 arg = pre*L2E = code*w' + b'
        // gi carries an extra L2E (LOG2_L2E); go carries 0.01 (LOG2_001).
        wi2 = wi * KNU;  const float bi2 = fmaf(-0.65f, wi, bi) * L2E + LOG2_L2E;
        wf2 = wf * KNU;  const float bf2 = fmaf(-0.65f, wf, bf) * L2E;
        wo2 = wo * KNU;  const float bo2 = fmaf(-0.65f, wo, bo) * L2E + LOG2_001;
        wg2 = -wg * KNU; bg2 = fmaf(-0.65f, wg, bg) * NL2E;
        #pragma unroll
        for (int u = 0; u < CH; ++u) {
            bi2u[u] = bi2 + DRFT * u;
            bf2u[u] = bf2 + DRFT * u;
            bo2u[u] = bo2 + DRFT * u;
        }
        GATEBODY(0)                         // prime gates for chunk 0
    } else {
        const int j = q * TPG + lt;
        const float wl = Wl_w[j], bl = Wl_b[j];
        wl2 = -wl * KNU; bl2 = fmaf(-0.65f, wl, bl) * NL2E;   // e^{-pre_l}
        pwlds[lt]       = proj_w[q * TPG + lt];
        pwlds[TPG + lt] = proj_w[Hv + q * TPG + lt];
        #pragma unroll
        for (int u = 0; u < CH; ++u) { bi2u[u]=0; bf2u[u]=0; bo2u[u]=0; }
    }
    __syncthreads();

    // Phase p: G0 runs chunk p; G1 produces gates[p+1]; G2 runs h-chain of
    // chunk p-1 and projection of chunk p-2. One barrier per phase.
    for (int p = 0; p < NCH + 2; ++p) {
        if (grp == 0) {
            if (p < NCH) {
                const float* gr = &glds[((p & 1) * CH) * 1024 + lt * 4];
                float Cv[CH], Pv[CH];
                #pragma unroll
                for (int u = 0; u < CH; ++u) {
                    const float4 g = *reinterpret_cast<const float4*>(gr + u * 1024);
                    C = fmaf(g.x * En, C, -(g.y * En));   // C = -L2E*c
                    Cv[u] = C;
                    Pv[u] = g.z * En;                     // 0.01*o_t
                    m = fmaf(g.w, En, m);                 // -= KNU*S (biased)
                    if (u == CH - 1) m += CREB8;          // drift rebase
                    En = fexp2(m);
                }
                float* cw = &cpa[((p & 1) * 4) * 1024 + lt * 4];
                #pragma unroll
                for (int pp = 0; pp < 4; ++pp) {
                    float4 v;
                    v.x = Cv[2*pp]; v.y = Pv[2*pp];
                    v.z = Cv[2*pp+1]; v.w = Pv[2*pp+1];
                    *reinterpret_cast<float4*>(cw + pp * 1024) = v;
                }
            }
        } else if (grp == 1) {
            if (p < NCH - 1) { GATEBODY(p + 1) }
        } else {
            if (p >= 1 && p <= NCH) {
                const int t2 = (p - 1) * CH;
                const float4 xq0 = *reinterpret_cast<const float4*>(xrow + t2);
                const float4 xq1 = *reinterpret_cast<const float4*>(xrow + t2 + 4);
                const float* cr = &cpa[(((p - 1) & 1) * 4) * 1024 + lt * 4];
                float* hw = &hlds[((p - 1) & 1) * 2304 + lt * 9];
                #pragma unroll
                for (int pp = 0; pp < 4; ++pp) {
                    const float4 cp4 = *reinterpret_cast<const float4*>(cr + pp * 1024);
                    const float xc0 = (pp==0)?xq0.x:(pp==1)?xq0.z:(pp==2)?xq1.x:xq1.z;
                    const float xc1 = (pp==0)?xq0.y:(pp==1)?xq0.w:(pp==2)?xq1.y:xq1.w;
                    const float el0 = fexp2(fmaf(xc0, wl2, bl2));
                    const float el1 = fexp2(fmaf(xc1, wl2, bl2));
                    const float B0 = 1.01f + el0, B1 = 1.01f + el1;
                    const float rB = frcp(B0 * B1);       // one rcp, 2 lambdas
                    const float A0 = 1.0f + fexp2(cp4.x); // 1+e^{-c}, (1,2]
                    const float A1 = 1.0f + fexp2(cp4.z);
                    const float rA = frcp(A0 * A1);       // one rcp, 2 sig(c)
                    h = fmaf(cp4.y, rA * A1, h) * fmaf(rB * B1, -0.01f, 1.0f);
                    hw[2 * pp] = h;
                    h = fmaf(cp4.w, rA * A0, h) * fmaf(rB * B0, -0.01f, 1.0f);
                    hw[2 * pp + 1] = h;
                }
            }
            if (p >= 2) {
                const float* hb  = &hlds[(p & 1) * 2304];
                const float* pwk = &pwlds[rk * TPG];
                float sum = 0.0f;
                #pragma unroll
                for (int i2 = 0; i2 < 16; ++i2) {
                    const int v  = (i2 + rseg) & 15;   // rotation: spread banks
                    const int jj = rseg * 16 + v;
                    sum = fmaf(hb[jj * 9 + rt], pwk[jj], sum);
                }
                sum += __shfl_xor(sum, 1, 64);
                sum += __shfl_xor(sum, 2, 64);
                sum += __shfl_xor(sum, 4, 64);
                sum += __shfl_xor(sum, 8, 64);
                if (rseg == 0)
                    atomicAdd(&orow[((p - 2) * CH + rt) * 2 + rk], sum);
            }
        }
        __syncthreads();
    }
}

extern "C" void kernel_launch(void* const* d_in, const int* in_sizes, int n_in,
                              void* d_out, int out_size, void* d_ws, size_t ws_size,
                              hipStream_t stream) {
    const float* x_codes = (const float*)d_in[0];
    const float* Wi_w = (const float*)d_in[1];
    const float* Wi_b = (const float*)d_in[2];
    const float* Wf_w = (const float*)d_in[3];
    const float* Wf_b = (const float*)d_in[4];
    const float* Wo_w = (const float*)d_in[5];
    const float* Wo_b = (const float*)d_in[6];
    const float* Wg_w = (const float*)d_in[7];
    const float* Wg_b = (const float*)d_in[8];
    const float* Wl_w = (const float*)d_in[9];
    const float* Wl_b = (const float*)d_in[10];
    const float* proj_w = (const float*)d_in[11];
    const float* proj_b = (const float*)d_in[12];
    const float* n_init = (const float*)d_in[13];
    float* out = (float*)d_out;

    init_out<<<out_size / 256, 256, 0, stream>>>(proj_b, out);
    cfc_scan<<<Bv * (Hv / TPG), NT, 0, stream>>>(
        x_codes, Wi_w, Wi_b, Wf_w, Wf_b, Wo_w, Wo_b, Wg_w, Wg_b, Wl_w, Wl_b,
        proj_w, n_init, out);
}